// Round 8
// baseline (283.217 us; speedup 1.0000x reference)
//
#include <hip/hip_runtime.h>
#include <hip/hip_bf16.h>

#define DIM    768
#define HEADS  12
#define DHEAD  64
#define BATCH  4
#define SEQ    2048
#define NROW   (BATCH * SEQ)   // 8192
#define QKVN   (3 * DIM)       // 2304
#define FACTOR 0.125f          // 64^-0.5
#define QSCALE 0.18033688011112042f  // FACTOR * log2(e), folded into Q

typedef __attribute__((ext_vector_type(8))) short short8;     // 8 bf16 = 4 VGPR
typedef __attribute__((ext_vector_type(4))) float floatx4;    // 16x16 C/D
typedef __attribute__((ext_vector_type(16))) float floatx16;  // 32x32 C/D

__device__ __forceinline__ floatx4 mfma16(short8 a, short8 b, floatx4 c) {
    return __builtin_amdgcn_mfma_f32_16x16x32_bf16(a, b, c, 0, 0, 0);
}
__device__ __forceinline__ floatx16 mfma32(short8 a, short8 b, floatx16 c) {
    return __builtin_amdgcn_mfma_f32_32x32x16_bf16(a, b, c, 0, 0, 0);
}

// async global->LDS, 16B per lane; lds base must be wave-uniform
__device__ __forceinline__ void glds16(const void* g, void* l) {
    __builtin_amdgcn_global_load_lds((const __attribute__((address_space(1))) void*)g,
                                     (__attribute__((address_space(3))) void*)l,
                                     16, 0, 0);
}

// branchless RNE fp32->bf16 (finite values only)
__device__ __forceinline__ short rne16(float f) {
    unsigned u = __builtin_bit_cast(unsigned, f);
    return (short)((u + 0x7fffu + ((u >> 16) & 1u)) >> 16);
}
__device__ __forceinline__ unsigned pack2(float lo, float hi) {
    unsigned ul = __builtin_bit_cast(unsigned, lo);
    unsigned uh = __builtin_bit_cast(unsigned, hi);
    ul = (ul + 0x7fffu + ((ul >> 16) & 1u)) >> 16;
    uh = (uh + 0x7fffu + ((uh >> 16) & 1u)) & 0xffff0000u;
    return ul | uh;
}

// XOR-swizzled tile addressing: 64 bf16 per row, swizzle 16B chunks.
__device__ __forceinline__ int swz8(int row, int col) {
    return (row << 6) + ((((col >> 3) ^ row) & 7) << 3) + (col & 7);
}

// ---------------------------------------------------------------------------
// x fp32 -> bf16
// ---------------------------------------------------------------------------
__global__ __launch_bounds__(256) void conv_bf16(const float* __restrict__ x,
                                                 short* __restrict__ xb) {
    int g = blockIdx.x * 256 + threadIdx.x;
    float4 v = ((const float4*)x)[g];
    uint2 o;
    o.x = pack2(v.x, v.y);
    o.y = pack2(v.z, v.w);
    ((uint2*)xb)[g] = o;
}

// ---------------------------------------------------------------------------
// W [K][N] fp32 -> Wt [N'][K] bf16.  permute=1 (W_qkv): col n = d*36+wh*12+h
// -> row n' = wh*768 + h*64 + d  (GEMM epilogue becomes (wh,h,d)-coalesced).
// ---------------------------------------------------------------------------
__global__ __launch_bounds__(256) void transpose_w(const float* __restrict__ W,
                                                   short* __restrict__ Wt,
                                                   int K, int N, int permute) {
    __shared__ short T[32][33];
    int n0 = blockIdx.x * 32, k0 = blockIdx.y * 32;
    int c = threadIdx.x & 31, r0 = threadIdx.x >> 5;
    for (int r = r0; r < 32; r += 8)
        T[r][c] = rne16(W[(size_t)(k0 + r) * N + n0 + c]);
    __syncthreads();
    for (int r = r0; r < 32; r += 8) {
        int n = n0 + r;
        int np;
        if (permute) {
            int d = n / 36, rem = n - d * 36;
            int which = rem / 12, h = rem - which * 12;
            np = which * 768 + h * 64 + d;
        } else {
            np = n;
        }
        Wt[(size_t)np * K + k0 + c] = T[c][r];
    }
}

// ---------------------------------------------------------------------------
// qkv = xb @ Wqkv (via permuted Wqt [2304][768]); glds-staged.
// Q pre-scaled by QSCALE so attention can use exp2(s) directly.
// ---------------------------------------------------------------------------
__global__ __launch_bounds__(256) void gemm_qkv(const short* __restrict__ A,
                                                const short* __restrict__ Bt,
                                                short* __restrict__ Qo,
                                                short* __restrict__ Ko,
                                                short* __restrict__ Vto) {
    __shared__ short As[128 * 64];
    __shared__ short Bs[128 * 64];
    const int tid = threadIdx.x;
    const int lane = tid & 63, wave = tid >> 6;
    const int l15 = lane & 15, quad = lane >> 4;

    // XCD swizzle: 8 XCDs x 8 m x 18 n = 1152 blocks
    const int flat = blockIdx.x;
    const int xcd = flat & 7;
    const int local = flat >> 3;
    const int mloc = local & 7, nloc = local >> 3;
    const int m0 = (xcd * 8 + mloc) * 128;
    const int n0 = nloc * 128;

    const int wm = (wave >> 1) * 64, wn = (wave & 1) * 64;
    const int r8 = wave * 8 + (lane >> 3);
    const int c8 = lane & 7;
    const int sc = ((c8 ^ (r8 & 7)) << 3);   // swizzled source chunk (elems)

    floatx4 acc[4][4] = {};
    for (int k0 = 0; k0 < DIM; k0 += 64) {
#pragma unroll
        for (int i = 0; i < 4; ++i) {
            int row = i * 32 + r8;
            glds16(&A[(size_t)(m0 + row) * DIM + k0 + sc], &As[(size_t)(i * 32 + wave * 8) * 64]);
            glds16(&Bt[(size_t)(n0 + row) * DIM + k0 + sc], &Bs[(size_t)(i * 32 + wave * 8) * 64]);
        }
        __syncthreads();
#pragma unroll
        for (int ks = 0; ks < 2; ++ks) {
            short8 a[4], b[4];
#pragma unroll
            for (int mt = 0; mt < 4; ++mt)
                a[mt] = *(const short8*)&As[swz8(wm + mt * 16 + l15, ks * 32 + quad * 8)];
#pragma unroll
            for (int nt = 0; nt < 4; ++nt)
                b[nt] = *(const short8*)&Bs[swz8(wn + nt * 16 + l15, ks * 32 + quad * 8)];
#pragma unroll
            for (int mt = 0; mt < 4; ++mt)
#pragma unroll
                for (int nt = 0; nt < 4; ++nt)
                    acc[mt][nt] = mfma16(a[mt], b[nt], acc[mt][nt]);
        }
        __syncthreads();
    }

    // ---- epilogue ----
    const int sn = n0 + wn;                 // 64-aligned
    const int which = sn / 768;
    const int h = (sn - which * 768) >> 6;
    const int bb = (m0 + wm) >> 11;
    const int tbase = (m0 + wm) & 2047;

    if (which != 2) {
        short* dst = (which == 0) ? Qo : Ko;
        const float scale = (which == 0) ? QSCALE : 1.0f;
        const size_t rowbase = ((size_t)(bb * HEADS + h) * SEQ + tbase) * DHEAD;
#pragma unroll
        for (int mt = 0; mt < 4; ++mt)
#pragma unroll
            for (int nt = 0; nt < 4; ++nt) {
                int d = nt * 16 + l15;
#pragma unroll
                for (int r = 0; r < 4; ++r) {
                    int tl = mt * 16 + quad * 4 + r;
                    dst[rowbase + (size_t)tl * DHEAD + d] = rne16(acc[mt][nt][r] * scale);
                }
            }
    } else {
        short* vld = ((wave < 2) ? As : Bs) + (wave & 1) * 4096;  // 64x64
#pragma unroll
        for (int mt = 0; mt < 4; ++mt)
#pragma unroll
            for (int nt = 0; nt < 4; ++nt) {
                int d = nt * 16 + l15;
                int tl = mt * 16 + quad * 4;
                int chunk = (tl >> 3) ^ (d & 7);
                int addr = (d << 6) + (chunk << 3) + (tl & 7);
                uint2 pk;
                pk.x = pack2(acc[mt][nt][0], acc[mt][nt][1]);
                pk.y = pack2(acc[mt][nt][2], acc[mt][nt][3]);
                *(uint2*)&vld[addr] = pk;
            }
    }
    __syncthreads();
    if (which == 2) {
        short* vld = ((wave < 2) ? As : Bs) + (wave & 1) * 4096;
        const size_t vbase = ((size_t)(bb * HEADS + h) * DHEAD) * SEQ;
#pragma unroll
        for (int i = 0; i < 8; ++i) {
            int c = lane + i * 64;
            int d = c >> 3, j = c & 7;
            int addr = (d << 6) + (((j ^ (d & 7)) & 7) << 3);
            uint4 v = *(const uint4*)&vld[addr];
            *(uint4*)&Vto[vbase + (size_t)d * SEQ + tbase + j * 8] = v;
        }
    }
}

// ---------------------------------------------------------------------------
// MFMA flash attention, 32x32x16 shapes, un-normalized exp2.
// 512 threads / 8 waves; waves pair up: pair p owns q-rows [p*32,p*32+32),
// wave (p,0) takes kv 0..31 of each 64-chunk, wave (p,1) takes kv 32..63.
// Partial O merged through LDS at the end; row-sum normalization folded in.
// Q fragments in registers; K|V glds-staged (16 KB, aliases Q staging).
// ---------------------------------------------------------------------------
__global__ __launch_bounds__(512, 6) void attn_mfma(const short* __restrict__ Q,
                                                    const short* __restrict__ K,
                                                    const short* __restrict__ Vt,
                                                    short* __restrict__ O) {
    __shared__ __align__(16) short buf[17408];  // 16K K|V / 16K P / 2K lsum

    const int tid = threadIdx.x;
    const int lane = tid & 63, wave = tid >> 6;
    const int l31 = lane & 31, hi = lane >> 5;
    const int pair = wave >> 1, kvh = wave & 1;
    const int bh = blockIdx.y;
    const int q0 = blockIdx.x * 128;
    const size_t base = (size_t)bh * SEQ * DHEAD;
    short* Ks = buf;
    short* Vs = buf + 4096;
    short* myP = buf + 8192 + wave * 1024;     // [q32][kv32] swizzled

    // ---- stage Q 128x64 via glds (region aliases K|V) ----
    const int srow = wave * 8 + (lane >> 3);
    const int ssc = (((lane & 7) ^ (srow & 7)) << 3);
#pragma unroll
    for (int i = 0; i < 2; ++i) {
        int row = i * 64 + srow;
        glds16(&Q[base + (size_t)(q0 + row) * DHEAD + ssc],
               &buf[(size_t)(i * 64 + wave * 8) * 64]);
    }
    __syncthreads();
    short8 qf[4];
#pragma unroll
    for (int s = 0; s < 4; ++s)
        qf[s] = *(const short8*)&buf[swz8(pair * 32 + l31, s * 16 + hi * 8)];
    __syncthreads();

    floatx16 o0 = {}, o1 = {};
    float lsum = 0.f;

    // loop-invariant P addresses
    int pw[4];
#pragma unroll
    for (int g = 0; g < 4; ++g)
        pw[g] = l31 * 32 + ((g ^ (l31 & 3)) << 3) + 4 * hi;
    const int pr0 = l31 * 32 + (((hi) ^ (l31 & 3)) << 3);
    const int pr1 = l31 * 32 + (((2 + hi) ^ (l31 & 3)) << 3);

    for (int j0 = 0; j0 < SEQ; j0 += 64) {
        glds16(&K[base + (size_t)(j0 + srow) * DHEAD + ssc], &Ks[(size_t)(wave * 8) * 64]);
        glds16(&Vt[base + (size_t)srow * SEQ + j0 + ssc], &Vs[(size_t)(wave * 8) * 64]);
        __syncthreads();

        // S^T tile [kv32][q32] = K_half . Q^T   (4 k-steps over d=64)
        floatx16 s = {};
#pragma unroll
        for (int st = 0; st < 4; ++st) {
            short8 kf = *(const short8*)&Ks[swz8(kvh * 32 + l31, st * 16 + hi * 8)];
            s = mfma32(kf, qf[st], s);
        }

        // p = exp2(s); reg r: kv = (r&3) + 8*(r>>2) + 4*hi (q = l31)
#pragma unroll
        for (int g = 0; g < 4; ++g) {
            float p0 = __builtin_amdgcn_exp2f(s[4 * g + 0]);
            float p1 = __builtin_amdgcn_exp2f(s[4 * g + 1]);
            float p2 = __builtin_amdgcn_exp2f(s[4 * g + 2]);
            float p3 = __builtin_amdgcn_exp2f(s[4 * g + 3]);
            lsum += (p0 + p1) + (p2 + p3);
            uint2 pk;
            pk.x = pack2(p0, p1);
            pk.y = pack2(p2, p3);
            *(uint2*)&myP[pw[g]] = pk;
        }

        // O += P V  (A = P rows, B = V^T rows; 2 d-tiles x 2 k-steps)
#pragma unroll
        for (int s2 = 0; s2 < 2; ++s2) {
            short8 a = *(const short8*)&myP[s2 ? pr1 : pr0];
            short8 b0 = *(const short8*)&Vs[swz8(l31, kvh * 32 + s2 * 16 + hi * 8)];
            short8 b1 = *(const short8*)&Vs[swz8(32 + l31, kvh * 32 + s2 * 16 + hi * 8)];
            o0 = mfma32(a, b0, o0);
            o1 = mfma32(a, b1, o1);
        }
        __syncthreads();
    }

    // ---- epilogue: pair merge + normalize + store ----
    float rs = lsum + __shfl_xor(lsum, 32);    // total over this wave's kv-half, q=l31
    float* Om = (float*)buf;                   // 4 pairs x 2048 floats (32 KB)
    float* Lx = (float*)(buf + 16384);         // 4 pairs x 32 floats
    if (wave & 1) {
        Lx[pair * 32 + l31] = rs;
#pragma unroll
        for (int r = 0; r < 16; ++r) {
            Om[pair * 2048 + r * 64 + hi * 32 + l31] = o0[r];
            Om[pair * 2048 + (16 + r) * 64 + hi * 32 + l31] = o1[r];
        }
    }
    __syncthreads();
    if (!(wave & 1)) {
        const int b = bh / HEADS, h = bh - b * HEADS;
        float inv = 1.f / (rs + Lx[pair * 32 + l31]);
        Lx[pair * 32 + l31] = inv;
#pragma unroll
        for (int r = 0; r < 16; ++r) {
            int qr = (r & 3) + 8 * (r >> 2) + 4 * hi;
            float invr = Lx[pair * 32 + qr];
            float v0 = o0[r] + Om[pair * 2048 + r * 64 + hi * 32 + l31];
            float v1 = o1[r] + Om[pair * 2048 + (16 + r) * 64 + hi * 32 + l31];
            size_t rowo = ((size_t)(b * SEQ + q0 + pair * 32 + qr)) * DIM + h * 64;
            O[rowo + l31] = rne16(v0 * invr);
            O[rowo + 32 + l31] = rne16(v1 * invr);
        }
    }
}

// ---------------------------------------------------------------------------
// out = attnB @ Wout (via Wot [768][768]), fp32 output; glds-staged.
// ---------------------------------------------------------------------------
__global__ __launch_bounds__(256) void gemm_out(const short* __restrict__ A,
                                                const short* __restrict__ Bt,
                                                float* __restrict__ out) {
    __shared__ short As[128 * 64];
    __shared__ short Bs[128 * 64];
    const int tid = threadIdx.x;
    const int lane = tid & 63, wave = tid >> 6;
    const int l15 = lane & 15, quad = lane >> 4;
    const int m0 = blockIdx.y * 128, n0 = blockIdx.x * 128;
    const int wm = (wave >> 1) * 64, wn = (wave & 1) * 64;
    const int r8 = wave * 8 + (lane >> 3);
    const int sc = (((lane & 7) ^ (r8 & 7)) << 3);

    floatx4 acc[4][4] = {};
    for (int k0 = 0; k0 < DIM; k0 += 64) {
#pragma unroll
        for (int i = 0; i < 4; ++i) {
            int row = i * 32 + r8;
            glds16(&A[(size_t)(m0 + row) * DIM + k0 + sc], &As[(size_t)(i * 32 + wave * 8) * 64]);
            glds16(&Bt[(size_t)(n0 + row) * DIM + k0 + sc], &Bs[(size_t)(i * 32 + wave * 8) * 64]);
        }
        __syncthreads();
#pragma unroll
        for (int ks = 0; ks < 2; ++ks) {
            short8 a[4], b[4];
#pragma unroll
            for (int mt = 0; mt < 4; ++mt)
                a[mt] = *(const short8*)&As[swz8(wm + mt * 16 + l15, ks * 32 + quad * 8)];
#pragma unroll
            for (int nt = 0; nt < 4; ++nt)
                b[nt] = *(const short8*)&Bs[swz8(wn + nt * 16 + l15, ks * 32 + quad * 8)];
#pragma unroll
            for (int mt = 0; mt < 4; ++mt)
#pragma unroll
                for (int nt = 0; nt < 4; ++nt)
                    acc[mt][nt] = mfma16(a[mt], b[nt], acc[mt][nt]);
        }
        __syncthreads();
    }

#pragma unroll
    for (int mt = 0; mt < 4; ++mt)
#pragma unroll
        for (int nt = 0; nt < 4; ++nt)
#pragma unroll
            for (int r = 0; r < 4; ++r) {
                int m = m0 + wm + mt * 16 + quad * 4 + r;
                int n = n0 + wn + nt * 16 + l15;
                out[(size_t)m * DIM + n] = acc[mt][nt][r];
            }
}

// ---------------------------------------------------------------------------
extern "C" void kernel_launch(void* const* d_in, const int* in_sizes, int n_in,
                              void* d_out, int out_size, void* d_ws, size_t ws_size,
                              hipStream_t stream) {
    const float* x    = (const float*)d_in[0];  // [4,2048,768] fp32
    const float* Wqkv = (const float*)d_in[1];  // [768,2304]  fp32
    const float* Wout = (const float*)d_in[2];  // [768,768]   fp32
    float* out = (float*)d_out;                 // [4,2048,768] fp32

    const size_t NE = (size_t)NROW * DIM;       // 6291456
    short* xb  = (short*)d_ws;                  // x bf16; later reused as attnB
    short* Wqt = xb + NE;                       // [2304][768] (col-permuted)
    short* Wot = Wqt + (size_t)QKVN * DIM;      // [768][768]
    short* Qw  = Wot + (size_t)DIM * DIM;       // [b,h,t,d] (pre-scaled)
    short* Kw  = Qw + NE;                       // [b,h,t,d]
    short* Vtw = Kw + NE;                       // [b,h,d,t]

    conv_bf16<<<NE / 4 / 256, 256, 0, stream>>>(x, xb);
    transpose_w<<<dim3(QKVN / 32, DIM / 32), 256, 0, stream>>>(Wqkv, Wqt, DIM, QKVN, 1);
    transpose_w<<<dim3(DIM / 32, DIM / 32), 256, 0, stream>>>(Wout, Wot, DIM, DIM, 0);
    gemm_qkv<<<8 * 8 * 18, 256, 0, stream>>>(xb, Wqt, Qw, Kw, Vtw);
    // xb (x in bf16) is dead after gemm_qkv -> reuse as attention output buffer
    attn_mfma<<<dim3(SEQ / 128, BATCH * HEADS), 512, 0, stream>>>(Qw, Kw, Vtw, xb);
    gemm_out<<<dim3(DIM / 128, NROW / 128), 256, 0, stream>>>(xb, Wot, out);
}

// Round 9
// 225.648 us; speedup vs baseline: 1.2551x; 1.2551x over previous
//
#include <hip/hip_runtime.h>
#include <hip/hip_bf16.h>

#define DIM    768
#define HEADS  12
#define DHEAD  64
#define BATCH  4
#define SEQ    2048
#define NROW   (BATCH * SEQ)   // 8192
#define QKVN   (3 * DIM)       // 2304
#define FACTOR 0.125f          // 64^-0.5
#define QSCALE 0.18033688011112042f  // FACTOR * log2(e), folded into Q

typedef __attribute__((ext_vector_type(8))) short short8;   // 8 bf16 = 4 VGPR
typedef __attribute__((ext_vector_type(4))) float floatx4;  // 16x16 C/D

__device__ __forceinline__ floatx4 mfma16(short8 a, short8 b, floatx4 c) {
    return __builtin_amdgcn_mfma_f32_16x16x32_bf16(a, b, c, 0, 0, 0);
}

// async global->LDS, 16B per lane; lds base must be wave-uniform,
// deposits at base + lane*16 (lane-ordered source REQUIRED for coalescing)
__device__ __forceinline__ void glds16(const void* g, void* l) {
    __builtin_amdgcn_global_load_lds((const __attribute__((address_space(1))) void*)g,
                                     (__attribute__((address_space(3))) void*)l,
                                     16, 0, 0);
}

// branchless RNE fp32->bf16 (finite values only)
__device__ __forceinline__ short rne16(float f) {
    unsigned u = __builtin_bit_cast(unsigned, f);
    return (short)((u + 0x7fffu + ((u >> 16) & 1u)) >> 16);
}
__device__ __forceinline__ unsigned pack2(float lo, float hi) {
    unsigned ul = __builtin_bit_cast(unsigned, lo);
    unsigned uh = __builtin_bit_cast(unsigned, hi);
    ul = (ul + 0x7fffu + ((ul >> 16) & 1u)) >> 16;
    uh = (uh + 0x7fffu + ((uh >> 16) & 1u)) & 0xffff0000u;
    return ul | uh;
}

// XOR-swizzled tile addressing: 64 bf16 per row, swizzle 16B chunks.
__device__ __forceinline__ int swz8(int row, int col) {
    return (row << 6) + ((((col >> 3) ^ row) & 7) << 3) + (col & 7);
}

// ---------------------------------------------------------------------------
// x fp32 -> bf16
// ---------------------------------------------------------------------------
__global__ __launch_bounds__(256) void conv_bf16(const float* __restrict__ x,
                                                 short* __restrict__ xb) {
    int g = blockIdx.x * 256 + threadIdx.x;
    float4 v = ((const float4*)x)[g];
    uint2 o;
    o.x = pack2(v.x, v.y);
    o.y = pack2(v.z, v.w);
    ((uint2*)xb)[g] = o;
}

// ---------------------------------------------------------------------------
// W [K][N] fp32 -> Wt [N'][K] bf16.  permute=1 (W_qkv): col n = d*36+wh*12+h
// -> row n' = wh*768 + h*64 + d  (GEMM epilogue becomes (wh,h,d)-coalesced).
// ---------------------------------------------------------------------------
__global__ __launch_bounds__(256) void transpose_w(const float* __restrict__ W,
                                                   short* __restrict__ Wt,
                                                   int K, int N, int permute) {
    __shared__ short T[32][33];
    int n0 = blockIdx.x * 32, k0 = blockIdx.y * 32;
    int c = threadIdx.x & 31, r0 = threadIdx.x >> 5;
    for (int r = r0; r < 32; r += 8)
        T[r][c] = rne16(W[(size_t)(k0 + r) * N + n0 + c]);
    __syncthreads();
    for (int r = r0; r < 32; r += 8) {
        int n = n0 + r;
        int np;
        if (permute) {
            int d = n / 36, rem = n - d * 36;
            int which = rem / 12, h = rem - which * 12;
            np = which * 768 + h * 64 + d;
        } else {
            np = n;
        }
        Wt[(size_t)np * K + k0 + c] = T[c][r];
    }
}

// ---------------------------------------------------------------------------
// qkv = xb @ Wqkv (via permuted Wqt [2304][768]); glds-staged.
// Outputs Q,K,V^T as XOR-swizzled 64x64 tiles: [bh][32 tiles][4096 shorts],
// byte-identical to the LDS image attn wants (so attn can glds lane-ordered).
// Q pre-scaled by QSCALE so attention can use exp2(s) directly.
// ---------------------------------------------------------------------------
__global__ __launch_bounds__(256) void gemm_qkv(const short* __restrict__ A,
                                                const short* __restrict__ Bt,
                                                short* __restrict__ Qo,
                                                short* __restrict__ Ko,
                                                short* __restrict__ Vto) {
    __shared__ short As[128 * 64];
    __shared__ short Bs[128 * 64];
    const int tid = threadIdx.x;
    const int lane = tid & 63, wave = tid >> 6;
    const int l15 = lane & 15, quad = lane >> 4;

    // XCD swizzle: 8 XCDs x 8 m x 18 n = 1152 blocks
    const int flat = blockIdx.x;
    const int xcd = flat & 7;
    const int local = flat >> 3;
    const int mloc = local & 7, nloc = local >> 3;
    const int m0 = (xcd * 8 + mloc) * 128;
    const int n0 = nloc * 128;

    const int wm = (wave >> 1) * 64, wn = (wave & 1) * 64;
    const int r8 = wave * 8 + (lane >> 3);
    const int c8 = lane & 7;
    const int sc = ((c8 ^ (r8 & 7)) << 3);   // swizzled source chunk (elems)

    floatx4 acc[4][4] = {};
    for (int k0 = 0; k0 < DIM; k0 += 64) {
#pragma unroll
        for (int i = 0; i < 4; ++i) {
            int row = i * 32 + r8;
            glds16(&A[(size_t)(m0 + row) * DIM + k0 + sc], &As[(size_t)(i * 32 + wave * 8) * 64]);
            glds16(&Bt[(size_t)(n0 + row) * DIM + k0 + sc], &Bs[(size_t)(i * 32 + wave * 8) * 64]);
        }
        __syncthreads();
#pragma unroll
        for (int ks = 0; ks < 2; ++ks) {
            short8 a[4], b[4];
#pragma unroll
            for (int mt = 0; mt < 4; ++mt)
                a[mt] = *(const short8*)&As[swz8(wm + mt * 16 + l15, ks * 32 + quad * 8)];
#pragma unroll
            for (int nt = 0; nt < 4; ++nt)
                b[nt] = *(const short8*)&Bs[swz8(wn + nt * 16 + l15, ks * 32 + quad * 8)];
#pragma unroll
            for (int mt = 0; mt < 4; ++mt)
#pragma unroll
                for (int nt = 0; nt < 4; ++nt)
                    acc[mt][nt] = mfma16(a[mt], b[nt], acc[mt][nt]);
        }
        __syncthreads();
    }

    // ---- epilogue ----
    const int sn = n0 + wn;                 // 64-aligned
    const int which = sn / 768;
    const int h = (sn - which * 768) >> 6;
    const int bb = (m0 + wm) >> 11;
    const int tbase = (m0 + wm) & 2047;
    const size_t tilebase = ((size_t)(bb * HEADS + h) * 32 + (tbase >> 6)) * 4096;

    if (which != 2) {
        // Q/K: scalar stores into the swizzled tile (same 128B lines as linear)
        short* dst = (which == 0) ? Qo : Ko;
        const float scale = (which == 0) ? QSCALE : 1.0f;
#pragma unroll
        for (int mt = 0; mt < 4; ++mt)
#pragma unroll
            for (int nt = 0; nt < 4; ++nt) {
                int d = nt * 16 + l15;
#pragma unroll
                for (int r = 0; r < 4; ++r) {
                    int tl = mt * 16 + quad * 4 + r;
                    dst[tilebase + swz8(tl, d)] = rne16(acc[mt][nt][r] * scale);
                }
            }
    } else {
        // V: build the swizzled V^T 64x64 tile in LDS (vld IS the tile image)
        short* vld = ((wave < 2) ? As : Bs) + (wave & 1) * 4096;  // 64x64
#pragma unroll
        for (int mt = 0; mt < 4; ++mt)
#pragma unroll
            for (int nt = 0; nt < 4; ++nt) {
                int d = nt * 16 + l15;
                int tl = mt * 16 + quad * 4;
                int chunk = (tl >> 3) ^ (d & 7);
                int addr = (d << 6) + (chunk << 3) + (tl & 7);   // = swz8(d, tl)
                uint2 pk;
                pk.x = pack2(acc[mt][nt][0], acc[mt][nt][1]);
                pk.y = pack2(acc[mt][nt][2], acc[mt][nt][3]);
                *(uint2*)&vld[addr] = pk;
            }
    }
    __syncthreads();
    if (which == 2) {
        // linear dump of the swizzled tile -> perfectly coalesced dwordx4
        short* vld = ((wave < 2) ? As : Bs) + (wave & 1) * 4096;
#pragma unroll
        for (int i = 0; i < 8; ++i) {
            int c = (i * 64 + lane) * 8;
            *(uint4*)&Vto[tilebase + c] = *(const uint4*)&vld[c];
        }
    }
}

// ---------------------------------------------------------------------------
// MFMA flash attention (r7 structure), un-normalized exp2 (Q pre-scaled).
// 512 threads / 8 waves; wave owns 16 q-rows. Q/K/V glds-staged lane-ordered
// from pre-swizzled tiles. 1D XCD-aware grid: bh%8 == xcd so each XCD's L2
// holds 6 heads' K+V (3 MB < 4 MB).
// ---------------------------------------------------------------------------
__global__ __launch_bounds__(512, 6) void attn_mfma(const short* __restrict__ Q,
                                                    const short* __restrict__ K,
                                                    const short* __restrict__ Vt,
                                                    short* __restrict__ O) {
    __shared__ __align__(16) short buf[8192];   // Q stage, then K(0..4095)|V(4096..)
    __shared__ __align__(16) short Ps[8192];    // per-wave P tiles [q16][kv64]

    const int tid = threadIdx.x;
    const int lane = tid & 63, wave = tid >> 6;
    const int l15 = lane & 15, quad = lane >> 4;
    const int flat = blockIdx.x;
    const int xcd = flat & 7, li = flat >> 3;      // li 0..95
    const int bh = xcd + (li % 6) * 8;             // bh % 8 == xcd
    const int q0 = (li / 6) * 128;
    const size_t base = (size_t)bh * SEQ * DHEAD;  // shorts; = bh*32 tiles
    const int wr = wave * 16;
    short* myP = Ps + wave * 1024;
    short* Ks = buf;
    short* Vs = buf + 4096;
    const int lane8 = lane * 8;

    // ---- stage Q (2 swizzled tiles, 16 KB) lane-ordered ----
    {
        size_t qtb = base + (size_t)(q0 >> 6) * 4096;
#pragma unroll
        for (int i = 0; i < 2; ++i)
            glds16(&Q[qtb + (size_t)(i * 8 + wave) * 512 + lane8],
                   &buf[(i * 8 + wave) * 512]);
    }
    __syncthreads();
    short8 qf[2];
#pragma unroll
    for (int ks = 0; ks < 2; ++ks)
        qf[ks] = *(const short8*)&buf[swz8(wr + l15, ks * 32 + quad * 8)];
    __syncthreads();   // Q in regs; buf now free for K|V

    floatx4 o[4] = {};
    float lsum = 0.f;

    for (int j0 = 0; j0 < SEQ; j0 += 64) {
        size_t ktb = base + (size_t)(j0 >> 6) * 4096 + wave * 512 + lane8;
        glds16(&K[ktb], &Ks[wave * 512]);
        glds16(&Vt[ktb], &Vs[wave * 512]);
        __syncthreads();

        // S^T = K Q^T : lane holds q = wr+l15, kv = kt*16 + quad*4 + r
        floatx4 s[4] = {};
#pragma unroll
        for (int ks = 0; ks < 2; ++ks) {
            short8 kf[4];
#pragma unroll
            for (int kt = 0; kt < 4; ++kt)
                kf[kt] = *(const short8*)&Ks[swz8(kt * 16 + l15, ks * 32 + quad * 8)];
#pragma unroll
            for (int kt = 0; kt < 4; ++kt)
                s[kt] = mfma16(kf[kt], qf[ks], s[kt]);
        }

        // p = exp2(s); pack 4 consecutive kv -> one b64 write into P[q][kv]
#pragma unroll
        for (int kt = 0; kt < 4; ++kt) {
            float p0 = __builtin_amdgcn_exp2f(s[kt][0]);
            float p1 = __builtin_amdgcn_exp2f(s[kt][1]);
            float p2 = __builtin_amdgcn_exp2f(s[kt][2]);
            float p3 = __builtin_amdgcn_exp2f(s[kt][3]);
            lsum += (p0 + p1) + (p2 + p3);
            uint2 pk;
            pk.x = pack2(p0, p1);
            pk.y = pack2(p2, p3);
            *(uint2*)&myP[swz8(l15, kt * 16 + quad * 4)] = pk;
        }

        // O += P V   (A from wave-local myP; per-wave DS ops are in-order)
#pragma unroll
        for (int ks = 0; ks < 2; ++ks) {
            short8 a = *(const short8*)&myP[swz8(l15, ks * 32 + quad * 8)];
            short8 b[4];
#pragma unroll
            for (int dt = 0; dt < 4; ++dt)
                b[dt] = *(const short8*)&Vs[swz8(dt * 16 + l15, ks * 32 + quad * 8)];
#pragma unroll
            for (int dt = 0; dt < 4; ++dt)
                o[dt] = mfma16(a, b[dt], o[dt]);
        }
        __syncthreads();
    }

    // epilogue: reduce row sums across quads (lane's lsum is for q-row l15),
    // redistribute 1/l to C-layout rows, normalize, store
    const int b = bh / HEADS, h = bh - b * HEADS;
    float rs = lsum;
    rs += __shfl_xor(rs, 16);
    rs += __shfl_xor(rs, 32);
    float invl = 1.f / rs;  // valid for q-row = l15
#pragma unroll
    for (int r = 0; r < 4; ++r) {
        float inv = __shfl(invl, quad * 4 + r);
        int t = q0 + wr + quad * 4 + r;
#pragma unroll
        for (int dt = 0; dt < 4; ++dt) {
            int d = dt * 16 + l15;
            O[((size_t)(b * SEQ + t)) * DIM + h * DHEAD + d] = rne16(o[dt][r] * inv);
        }
    }
}

// ---------------------------------------------------------------------------
// out = attnB @ Wout (via Wot [768][768]), fp32 output; glds-staged.
// ---------------------------------------------------------------------------
__global__ __launch_bounds__(256) void gemm_out(const short* __restrict__ A,
                                                const short* __restrict__ Bt,
                                                float* __restrict__ out) {
    __shared__ short As[128 * 64];
    __shared__ short Bs[128 * 64];
    const int tid = threadIdx.x;
    const int lane = tid & 63, wave = tid >> 6;
    const int l15 = lane & 15, quad = lane >> 4;
    const int m0 = blockIdx.y * 128, n0 = blockIdx.x * 128;
    const int wm = (wave >> 1) * 64, wn = (wave & 1) * 64;
    const int r8 = wave * 8 + (lane >> 3);
    const int sc = (((lane & 7) ^ (r8 & 7)) << 3);

    floatx4 acc[4][4] = {};
    for (int k0 = 0; k0 < DIM; k0 += 64) {
#pragma unroll
        for (int i = 0; i < 4; ++i) {
            int row = i * 32 + r8;
            glds16(&A[(size_t)(m0 + row) * DIM + k0 + sc], &As[(size_t)(i * 32 + wave * 8) * 64]);
            glds16(&Bt[(size_t)(n0 + row) * DIM + k0 + sc], &Bs[(size_t)(i * 32 + wave * 8) * 64]);
        }
        __syncthreads();
#pragma unroll
        for (int ks = 0; ks < 2; ++ks) {
            short8 a[4], b[4];
#pragma unroll
            for (int mt = 0; mt < 4; ++mt)
                a[mt] = *(const short8*)&As[swz8(wm + mt * 16 + l15, ks * 32 + quad * 8)];
#pragma unroll
            for (int nt = 0; nt < 4; ++nt)
                b[nt] = *(const short8*)&Bs[swz8(wn + nt * 16 + l15, ks * 32 + quad * 8)];
#pragma unroll
            for (int mt = 0; mt < 4; ++mt)
#pragma unroll
                for (int nt = 0; nt < 4; ++nt)
                    acc[mt][nt] = mfma16(a[mt], b[nt], acc[mt][nt]);
        }
        __syncthreads();
    }

#pragma unroll
    for (int mt = 0; mt < 4; ++mt)
#pragma unroll
        for (int nt = 0; nt < 4; ++nt)
#pragma unroll
            for (int r = 0; r < 4; ++r) {
                int m = m0 + wm + mt * 16 + quad * 4 + r;
                int n = n0 + wn + nt * 16 + l15;
                out[(size_t)m * DIM + n] = acc[mt][nt][r];
            }
}

// ---------------------------------------------------------------------------
extern "C" void kernel_launch(void* const* d_in, const int* in_sizes, int n_in,
                              void* d_out, int out_size, void* d_ws, size_t ws_size,
                              hipStream_t stream) {
    const float* x    = (const float*)d_in[0];  // [4,2048,768] fp32
    const float* Wqkv = (const float*)d_in[1];  // [768,2304]  fp32
    const float* Wout = (const float*)d_in[2];  // [768,768]   fp32
    float* out = (float*)d_out;                 // [4,2048,768] fp32

    const size_t NE = (size_t)NROW * DIM;       // 6291456
    short* xb  = (short*)d_ws;                  // x bf16; later reused as attnB
    short* Wqt = xb + NE;                       // [2304][768] (col-permuted)
    short* Wot = Wqt + (size_t)QKVN * DIM;      // [768][768]
    short* Qw  = Wot + (size_t)DIM * DIM;       // swizzled tiles (pre-scaled)
    short* Kw  = Qw + NE;                       // swizzled tiles
    short* Vtw = Kw + NE;                       // swizzled V^T tiles

    conv_bf16<<<NE / 4 / 256, 256, 0, stream>>>(x, xb);
    transpose_w<<<dim3(QKVN / 32, DIM / 32), 256, 0, stream>>>(Wqkv, Wqt, DIM, QKVN, 1);
    transpose_w<<<dim3(DIM / 32, DIM / 32), 256, 0, stream>>>(Wout, Wot, DIM, DIM, 0);
    gemm_qkv<<<8 * 8 * 18, 256, 0, stream>>>(xb, Wqt, Qw, Kw, Vtw);
    // xb (x in bf16) is dead after gemm_qkv -> reuse as attention output buffer
    attn_mfma<<<768, 512, 0, stream>>>(Qw, Kw, Vtw, xb);
    gemm_out<<<dim3(DIM / 128, NROW / 128), 256, 0, stream>>>(xb, Wot, out);
}